// Round 6
// baseline (1826.088 us; speedup 1.0000x reference)
//
#include <hip/hip_runtime.h>
#include <math.h>

#define BB 128
#define TT 2048
#define II 128
#define UU 256
#define OO 128

// LDS-only barrier: orders LDS ops without draining vmcnt (global stores /
// prefetch loads stay in flight). sched_barrier(0) pins ordering (rule 18).
__device__ __forceinline__ void bar_lds() {
    __builtin_amdgcn_sched_barrier(0);
    asm volatile("s_waitcnt lgkmcnt(0)" ::: "memory");
    __builtin_amdgcn_s_barrier();
    __builtin_amdgcn_sched_barrier(0);
}

__device__ __forceinline__ void fma4(float4& a, const float4 w, const float4 h) {
    a.x = fmaf(w.x, h.x, a.x);
    a.y = fmaf(w.y, h.y, a.y);
    a.z = fmaf(w.z, h.z, a.z);
    a.w = fmaf(w.w, h.w, a.w);
}

// DPP cross-lane exchanges (pure VALU, no LDS pipe):
__device__ __forceinline__ float dpp_xor1(float x) {   // quad_perm [1,0,3,2]
    return __int_as_float(__builtin_amdgcn_mov_dpp(__float_as_int(x), 0xB1, 0xF, 0xF, true));
}
__device__ __forceinline__ float dpp_xor2(float x) {   // quad_perm [2,3,0,1]
    return __int_as_float(__builtin_amdgcn_mov_dpp(__float_as_int(x), 0x4E, 0xF, 0xF, true));
}
__device__ __forceinline__ float dpp_xor8(float x) {   // row_ror:8 (xor8 in 16)
    return __int_as_float(__builtin_amdgcn_mov_dpp(__float_as_int(x), 0x128, 0xF, 0xF, true));
}
__device__ __forceinline__ float swz_xor4(float x) {   // ds_swizzle xor4
    return __int_as_float(__builtin_amdgcn_ds_swizzle(__float_as_int(x), 0x101F));
}

// 4-row value-splitting butterfly. CONTRACT: lane ends with the sum of row
// (tid & 3) of this group over the chunks of lane-bits {0,1,3}. s0..s3 are
// this lane's k-chunk partials for rows u0+0..3.
__device__ __forceinline__ float reduce4(float s0, float s1, float s2, float s3,
                                         int tid) {
    const bool e1 = (tid & 1), e2 = (tid & 2);
    float z0 = e1 ? s0 : s1;
    float z1 = e1 ? s2 : s3;
    float A0 = (e1 ? s1 : s0) + dpp_xor1(z0);   // row bit0
    float A1 = (e1 ? s3 : s2) + dpp_xor1(z1);   // row 2+bit0
    float z2 = e2 ? A0 : A1;
    float C = (e2 ? A1 : A0) + dpp_xor2(z2);    // row (tid&3)
    return C + dpp_xor8(C);                      // + lane-bit-3 chunks
}

// ---------------- Kernel 1: input projection ----------------
// (unchanged from validated round-4 version)
__global__ __launch_bounds__(512, 2) void k_inproj(
    const float* __restrict__ x, const float* __restrict__ Wih,
    const float* __restrict__ bih, const float* __restrict__ bhh,
    float* __restrict__ xp)
{
    __shared__ __align__(16) float xs[64 * 160];   // 64 rows x 8 chunks x 20
    const int tid = threadIdx.x;
    const int kk = (tid & 3) | ((tid >> 1) & 4);   // bits 0,1,3
    const int G  = ((tid >> 2) & 1) | ((tid >> 4) << 1);   // 0..63
    const int u0 = G * 4;
    float4 w[4][4];
    #pragma unroll
    for (int r = 0; r < 4; ++r)
        #pragma unroll
        for (int j = 0; j < 4; ++j)
            w[r][j] = *reinterpret_cast<const float4*>(
                &Wih[(size_t)(u0 + r) * II + kk * 16 + j * 4]);
    const int r3 = tid & 3;                        // matches reduce4 contract
    const int uw = u0 + r3;
    const float bias = bih[uw] + bhh[uw];
    const bool writer = (tid & 8) == 0;
    const int ntiles = (BB * TT) / 64;             // 4096
    for (int tile = blockIdx.x; tile < ntiles; tile += gridDim.x) {
        const size_t rowbase = (size_t)tile * 64;
        const float4* xg = reinterpret_cast<const float4*>(x + rowbase * II);
        #pragma unroll
        for (int i = 0; i < 4; ++i) {
            int v = tid + i * 512;                 // 0..2047 float4s
            int row = v >> 5, q = v & 31;
            float4 val = xg[v];
            *reinterpret_cast<float4*>(&xs[row * 160 + (q >> 2) * 20 + (q & 3) * 4]) = val;
        }
        __syncthreads();
        for (int r = 0; r < 64; ++r) {
            const float4* hrow = reinterpret_cast<const float4*>(&xs[r * 160 + kk * 20]);
            float4 a0 = {0,0,0,0}, a1 = {0,0,0,0}, a2 = {0,0,0,0}, a3 = {0,0,0,0};
            #pragma unroll
            for (int j = 0; j < 4; ++j) {
                float4 hv = hrow[j];
                fma4(a0, w[0][j], hv); fma4(a1, w[1][j], hv);
                fma4(a2, w[2][j], hv); fma4(a3, w[3][j], hv);
            }
            float s0 = (a0.x + a0.y) + (a0.z + a0.w);
            float s1 = (a1.x + a1.y) + (a1.z + a1.w);
            float s2 = (a2.x + a2.y) + (a2.z + a2.w);
            float s3 = (a3.x + a3.y) + (a3.z + a3.w);
            float D = reduce4(s0, s1, s2, s3, tid);
            if (writer) xp[(rowbase + r) * UU + uw] = D + bias;
        }
        __syncthreads();
    }
}

// ---------------- Kernel 2: serial recurrence ----------------
// 1 block/batch, 1024 thr (4 waves/SIMD). kk = tid&15 -> 16 chunks of
// 16 floats (stride 20, 2-way max on reads = free). G = tid>>4 -> 64 groups
// x 4 u-rows; per thread 4 ds_read_b128 feed 64 FMA (half of r5's LDS
// traffic at same wave count). Reduce: validated reduce4 (bits 0,1,3) +
// ds_swizzle xor4 (bit 2). 4 copies per u (bits 2,3): (0,0)->LDS masked,
// (4,0)->global h_raw. ONE barrier per step.
__global__ __launch_bounds__(1024, 4) void k_rnn(
    const float* __restrict__ Whh, float* __restrict__ xph)
{
    __shared__ __align__(16) float hc[2 * 320];    // 2 bufs x 16 chunks x 20
    const int tid = threadIdx.x;
    const int kk = tid & 15;                       // 16 chunks
    const int G  = tid >> 4;                       // 64 groups
    const int u0 = G * 4;
    float4 w[4][4];
    #pragma unroll
    for (int r = 0; r < 4; ++r)
        #pragma unroll
        for (int j = 0; j < 4; ++j)
            w[r][j] = *reinterpret_cast<const float4*>(
                &Whh[(size_t)(u0 + r) * UU + kk * 16 + j * 4]);
    const int uw = u0 + (tid & 3);                 // u this lane finalizes
    const bool ldswr  = (tid & 12) == 0;
    const bool globwr = (tid & 12) == 4;
    const bool kill = (uw == 3) || (uw == 7);
    const int wslot = (uw >> 4) * 20 + (uw & 15);  // LDS h slot for uw

    if (tid < 160) *reinterpret_cast<float4*>(&hc[tid * 4]) = (float4){0,0,0,0};
    __syncthreads();

    float* rowp = xph + (size_t)blockIdx.x * (size_t)TT * UU;
    float xpv = rowp[uw];
    float xpn = rowp[UU + uw];

    auto step = [&](int t, int p) {
        int tn = t + 2; tn = (tn < TT) ? tn : (TT - 1);      // branchless clamp
        float xpn2 = rowp[(size_t)tn * UU + uw];
        const float4* hb = reinterpret_cast<const float4*>(&hc[p * 320 + kk * 20]);
        float4 a0 = {0,0,0,0}, a1 = {0,0,0,0}, a2 = {0,0,0,0}, a3 = {0,0,0,0};
        #pragma unroll
        for (int j = 0; j < 4; ++j) {
            float4 hv = hb[j];
            fma4(a0, w[0][j], hv); fma4(a1, w[1][j], hv);
            fma4(a2, w[2][j], hv); fma4(a3, w[3][j], hv);
        }
        float s0 = (a0.x + a0.y) + (a0.z + a0.w);
        float s1 = (a1.x + a1.y) + (a1.z + a1.w);
        float s2 = (a2.x + a2.y) + (a2.z + a2.w);
        float s3 = (a3.x + a3.y) + (a3.z + a3.w);
        float C = reduce4(s0, s1, s2, s3, tid);    // bits 0,1,3; row tid&3
        float D = C + swz_xor4(C);                 // + bit2 chunks -> full sum
        float s = D + xpv;
        float hr = 1.0f - 2.0f / (__expf(2.0f * s) + 1.0f);
        if (globwr) {
            rowp[(size_t)t * UU + uw] = hr;                  // h_raw
        } else if (ldswr) {
            hc[(p ^ 1) * 320 + wslot] = kill ? 0.f : hr;     // masked carry
        }
        bar_lds();
        xpv = xpn; xpn = xpn2;
    };
    for (int t = 0; t < TT; t += 2) { step(t, 0); step(t + 1, 1); }
}

// ---------------- Kernel 3: readout + mask fix-up ----------------
// (unchanged from validated round-4 version)
__global__ __launch_bounds__(512, 2) void k_readout(
    const float* __restrict__ Wfc, const float* __restrict__ bfc,
    float* __restrict__ hraw, float* __restrict__ outR)
{
    __shared__ __align__(16) float hs[32 * 320];   // 32 rows x 16 chunks x 20
    const int tid = threadIdx.x;
    const int kk = tid & 15;
    const int G  = tid >> 4;                       // 0..31
    const int o0 = G * 4;
    float4 w[4][4];
    #pragma unroll
    for (int r = 0; r < 4; ++r)
        #pragma unroll
        for (int j = 0; j < 4; ++j)
            w[r][j] = *reinterpret_cast<const float4*>(
                &Wfc[(size_t)(o0 + r) * UU + kk * 16 + j * 4]);
    const int ow = o0 + (tid & 3);                 // matches reduce contract
    const float bias = bfc[ow];
    const bool writer = (tid & 12) == 0;
    const int ntiles = (BB * TT) / 32;             // 8192
    for (int tile = blockIdx.x; tile < ntiles; tile += gridDim.x) {
        const size_t rowbase = (size_t)tile * 32;
        const float4* hg = reinterpret_cast<const float4*>(hraw + rowbase * UU);
        #pragma unroll
        for (int i = 0; i < 4; ++i) {
            int v = tid + i * 512;                 // 0..2047 float4s
            int row = v >> 6, q = v & 63;
            float4 val = hg[v];
            *reinterpret_cast<float4*>(&hs[row * 320 + (q >> 2) * 20 + (q & 3) * 4]) = val;
        }
        __syncthreads();
        // raw values staged: zero killed units in the global hs output
        if (tid < 64) {
            int r = tid >> 1, c = (tid & 1) ? 7 : 3;
            hraw[(rowbase + r) * UU + c] = 0.f;
        }
        for (int r = 0; r < 32; ++r) {
            const float4* hrow = reinterpret_cast<const float4*>(&hs[r * 320 + kk * 20]);
            float4 a0 = {0,0,0,0}, a1 = {0,0,0,0}, a2 = {0,0,0,0}, a3 = {0,0,0,0};
            #pragma unroll
            for (int j = 0; j < 4; ++j) {
                float4 hv = hrow[j];
                fma4(a0, w[0][j], hv); fma4(a1, w[1][j], hv);
                fma4(a2, w[2][j], hv); fma4(a3, w[3][j], hv);
            }
            float s0 = (a0.x + a0.y) + (a0.z + a0.w);
            float s1 = (a1.x + a1.y) + (a1.z + a1.w);
            float s2 = (a2.x + a2.y) + (a2.z + a2.w);
            float s3 = (a3.x + a3.y) + (a3.z + a3.w);
            // stage1/2: resolve row bits 0,1 (same as reduce4, sans xor8)
            const bool e1 = (tid & 1), e2 = (tid & 2);
            float z0 = e1 ? s0 : s1;
            float z1 = e1 ? s2 : s3;
            float A0 = (e1 ? s1 : s0) + dpp_xor1(z0);
            float A1 = (e1 ? s3 : s2) + dpp_xor1(z1);
            float z2 = e2 ? A0 : A1;
            float C = (e2 ? A1 : A0) + dpp_xor2(z2);
            float C2 = C + dpp_xor8(C);            // + bit3 half
            float D  = C2 + swz_xor4(C2);          // + bit2 half (all 16 kk)
            if (writer) outR[(rowbase + r) * OO + ow] = D + bias;
        }
        __syncthreads();
    }
}

extern "C" void kernel_launch(void* const* d_in, const int* in_sizes, int n_in,
                              void* d_out, int out_size, void* d_ws, size_t ws_size,
                              hipStream_t stream) {
    const float* x   = (const float*)d_in[0];
    const float* Wih = (const float*)d_in[1];
    const float* Whh = (const float*)d_in[2];
    const float* bih = (const float*)d_in[3];
    const float* bhh = (const float*)d_in[4];
    const float* Wfc = (const float*)d_in[5];
    const float* bfc = (const float*)d_in[6];
    float* outR = (float*)d_out;                       // readouts [B,T,O]
    float* outH = outR + (size_t)BB * TT * OO;         // hs       [B,T,U]

    k_inproj<<<512, 512, 0, stream>>>(x, Wih, bih, bhh, outH);
    k_rnn<<<128, 1024, 0, stream>>>(Whh, outH);
    k_readout<<<512, 512, 0, stream>>>(Wfc, bfc, outH, outR);
}

// Round 7
// 1620.485 us; speedup vs baseline: 1.1269x; 1.1269x over previous
//
#include <hip/hip_runtime.h>
#include <math.h>

#define BB 128
#define TT 2048
#define II 128
#define UU 256
#define OO 128

typedef __attribute__((ext_vector_type(8))) short bf16x8;
typedef __attribute__((ext_vector_type(4))) float f32x4;

// LDS-only barrier: orders LDS ops without draining vmcnt (global stores /
// prefetch loads stay in flight). sched_barrier(0) pins ordering (rule 18).
__device__ __forceinline__ void bar_lds() {
    __builtin_amdgcn_sched_barrier(0);
    asm volatile("s_waitcnt lgkmcnt(0)" ::: "memory");
    __builtin_amdgcn_s_barrier();
    __builtin_amdgcn_sched_barrier(0);
}

__device__ __forceinline__ void fma4(float4& a, const float4 w, const float4 h) {
    a.x = fmaf(w.x, h.x, a.x);
    a.y = fmaf(w.y, h.y, a.y);
    a.z = fmaf(w.z, h.z, a.z);
    a.w = fmaf(w.w, h.w, a.w);
}

// DPP cross-lane exchanges (pure VALU, no LDS pipe):
__device__ __forceinline__ float dpp_xor1(float x) {   // quad_perm [1,0,3,2]
    return __int_as_float(__builtin_amdgcn_mov_dpp(__float_as_int(x), 0xB1, 0xF, 0xF, true));
}
__device__ __forceinline__ float dpp_xor2(float x) {   // quad_perm [2,3,0,1]
    return __int_as_float(__builtin_amdgcn_mov_dpp(__float_as_int(x), 0x4E, 0xF, 0xF, true));
}
__device__ __forceinline__ float dpp_xor8(float x) {   // row_ror:8 (xor8 in 16)
    return __int_as_float(__builtin_amdgcn_mov_dpp(__float_as_int(x), 0x128, 0xF, 0xF, true));
}
__device__ __forceinline__ float swz_xor4(float x) {   // ds_swizzle xor4
    return __int_as_float(__builtin_amdgcn_ds_swizzle(__float_as_int(x), 0x101F));
}

// float -> bf16 round-to-nearest-even
__device__ __forceinline__ short f2bf(float f) {
    unsigned u = __float_as_uint(f);
    unsigned r = (u + 0x7FFFu + ((u >> 16) & 1u)) >> 16;
    return (short)r;
}

// 4-row value-splitting butterfly. CONTRACT: lane ends with the sum of row
// (tid & 3) of this group over the chunks of lane-bits {0,1,3}.
__device__ __forceinline__ float reduce4(float s0, float s1, float s2, float s3,
                                         int tid) {
    const bool e1 = (tid & 1), e2 = (tid & 2);
    float z0 = e1 ? s0 : s1;
    float z1 = e1 ? s2 : s3;
    float A0 = (e1 ? s1 : s0) + dpp_xor1(z0);   // row bit0
    float A1 = (e1 ? s3 : s2) + dpp_xor1(z1);   // row 2+bit0
    float z2 = e2 ? A0 : A1;
    float C = (e2 ? A1 : A0) + dpp_xor2(z2);    // row (tid&3)
    return C + dpp_xor8(C);                      // + lane-bit-3 chunks
}

// ---------------- Kernel 1: input projection ----------------
// (unchanged, validated since round 4)
__global__ __launch_bounds__(512, 2) void k_inproj(
    const float* __restrict__ x, const float* __restrict__ Wih,
    const float* __restrict__ bih, const float* __restrict__ bhh,
    float* __restrict__ xp)
{
    __shared__ __align__(16) float xs[64 * 160];   // 64 rows x 8 chunks x 20
    const int tid = threadIdx.x;
    const int kk = (tid & 3) | ((tid >> 1) & 4);   // bits 0,1,3
    const int G  = ((tid >> 2) & 1) | ((tid >> 4) << 1);   // 0..63
    const int u0 = G * 4;
    float4 w[4][4];
    #pragma unroll
    for (int r = 0; r < 4; ++r)
        #pragma unroll
        for (int j = 0; j < 4; ++j)
            w[r][j] = *reinterpret_cast<const float4*>(
                &Wih[(size_t)(u0 + r) * II + kk * 16 + j * 4]);
    const int r3 = tid & 3;                        // matches reduce4 contract
    const int uw = u0 + r3;
    const float bias = bih[uw] + bhh[uw];
    const bool writer = (tid & 8) == 0;
    const int ntiles = (BB * TT) / 64;             // 4096
    for (int tile = blockIdx.x; tile < ntiles; tile += gridDim.x) {
        const size_t rowbase = (size_t)tile * 64;
        const float4* xg = reinterpret_cast<const float4*>(x + rowbase * II);
        #pragma unroll
        for (int i = 0; i < 4; ++i) {
            int v = tid + i * 512;                 // 0..2047 float4s
            int row = v >> 5, q = v & 31;
            float4 val = xg[v];
            *reinterpret_cast<float4*>(&xs[row * 160 + (q >> 2) * 20 + (q & 3) * 4]) = val;
        }
        __syncthreads();
        for (int r = 0; r < 64; ++r) {
            const float4* hrow = reinterpret_cast<const float4*>(&xs[r * 160 + kk * 20]);
            float4 a0 = {0,0,0,0}, a1 = {0,0,0,0}, a2 = {0,0,0,0}, a3 = {0,0,0,0};
            #pragma unroll
            for (int j = 0; j < 4; ++j) {
                float4 hv = hrow[j];
                fma4(a0, w[0][j], hv); fma4(a1, w[1][j], hv);
                fma4(a2, w[2][j], hv); fma4(a3, w[3][j], hv);
            }
            float s0 = (a0.x + a0.y) + (a0.z + a0.w);
            float s1 = (a1.x + a1.y) + (a1.z + a1.w);
            float s2 = (a2.x + a2.y) + (a2.z + a2.w);
            float s3 = (a3.x + a3.y) + (a3.z + a3.w);
            float D = reduce4(s0, s1, s2, s3, tid);
            if (writer) xp[(rowbase + r) * UU + uw] = D + bias;
        }
        __syncthreads();
    }
}

// ---------------- Kernel 2: serial recurrence (MFMA) ----------------
// 1 block/batch, 512 thr = 8 waves (2/SIMD). Per step the 256x256 GEMV runs
// on the matrix pipe: h (bf16, replicated across all 16 M-rows of A) x
// W_hh^T-slices (bf16 B fragments, 2 n-tiles x 8 k-tiles in 64 VGPRs/lane).
// All D rows are identical (A rows replicated) -> no cross-lane reduce:
// lane holds result for u = w*32 + (g&1)*16 + (lane&15) in acc[0] (C/D map
// col=lane&15, m89-verified). g<2 lanes write h_raw (fp32) to global;
// g>=2 lanes write masked bf16 h to the LDS double buffer. ONE barrier/step.
__global__ __launch_bounds__(512, 2) void k_rnn(
    const float* __restrict__ Whh, float* __restrict__ xph)
{
    __shared__ __align__(16) short hbuf[2 * 256];  // 2 x 256 bf16 = 1 KB
    const int tid = threadIdx.x;
    const int w = tid >> 6;          // wave 0..7 -> u-range w*32..w*32+31
    const int lane = tid & 63;
    const int g = lane >> 4;         // k-group (A/B fragment row-group)
    const int c = lane & 15;         // tile column
    // B fragments: lane holds W_hh[u][kt*32 + g*8 .. +7] as 8 bf16.
    bf16x8 bq[2][8];
    #pragma unroll
    for (int q = 0; q < 2; ++q) {
        const int ub = w * 32 + q * 16 + c;
        #pragma unroll
        for (int kt = 0; kt < 8; ++kt) {
            const float* wp = &Whh[(size_t)ub * UU + kt * 32 + g * 8];
            float4 va = *reinterpret_cast<const float4*>(wp);
            float4 vb = *reinterpret_cast<const float4*>(wp + 4);
            bf16x8 v;
            v[0] = f2bf(va.x); v[1] = f2bf(va.y);
            v[2] = f2bf(va.z); v[3] = f2bf(va.w);
            v[4] = f2bf(vb.x); v[5] = f2bf(vb.y);
            v[6] = f2bf(vb.z); v[7] = f2bf(vb.w);
            bq[q][kt] = v;
        }
    }
    const int q = g & 1;                           // which n-tile this lane owns
    const int uxp = w * 32 + q * 16 + c;           // u this lane finalizes
    const bool gl = (g < 2);                       // global writer vs LDS writer
    const bool kill = (uxp == 3) || (uxp == 7);

    if (tid < 256) reinterpret_cast<int*>(hbuf)[tid] = 0;   // h0 = 0, both bufs
    __syncthreads();

    float* rowp = xph + (size_t)blockIdx.x * (size_t)TT * UU;
    float xpv = rowp[uxp];
    float xpn = rowp[UU + uxp];

    auto step = [&](int t, int p) {
        int tn = t + 2; tn = (tn < TT) ? tn : (TT - 1);     // branchless clamp
        float xpn2 = rowp[(size_t)tn * UU + uxp];
        const bf16x8* hb = reinterpret_cast<const bf16x8*>(hbuf + p * 256);
        f32x4 acc0 = {0.f, 0.f, 0.f, 0.f};
        f32x4 acc1 = {0.f, 0.f, 0.f, 0.f};
        #pragma unroll
        for (int kt = 0; kt < 8; ++kt) {
            bf16x8 a = hb[kt * 4 + g];             // 16-way broadcast, 4 banks
            acc0 = __builtin_amdgcn_mfma_f32_16x16x32_bf16(a, bq[0][kt], acc0, 0, 0, 0);
            acc1 = __builtin_amdgcn_mfma_f32_16x16x32_bf16(a, bq[1][kt], acc1, 0, 0, 0);
        }
        float Dres = (q == 0) ? acc0[0] : acc1[0]; // all acc rows identical
        float s = Dres + xpv;
        float hr = 1.0f - 2.0f / (__expf(2.0f * s) + 1.0f);
        if (gl) {
            rowp[(size_t)t * UU + uxp] = hr;                   // h_raw (fp32)
        } else {
            hbuf[(p ^ 1) * 256 + uxp] = kill ? (short)0 : f2bf(hr); // carry
        }
        bar_lds();
        xpv = xpn; xpn = xpn2;
    };
    for (int t = 0; t < TT; t += 2) { step(t, 0); step(t + 1, 1); }
}

// ---------------- Kernel 3: readout + mask fix-up ----------------
// (unchanged, validated since round 4)
__global__ __launch_bounds__(512, 2) void k_readout(
    const float* __restrict__ Wfc, const float* __restrict__ bfc,
    float* __restrict__ hraw, float* __restrict__ outR)
{
    __shared__ __align__(16) float hs[32 * 320];   // 32 rows x 16 chunks x 20
    const int tid = threadIdx.x;
    const int kk = tid & 15;
    const int G  = tid >> 4;                       // 0..31
    const int o0 = G * 4;
    float4 w[4][4];
    #pragma unroll
    for (int r = 0; r < 4; ++r)
        #pragma unroll
        for (int j = 0; j < 4; ++j)
            w[r][j] = *reinterpret_cast<const float4*>(
                &Wfc[(size_t)(o0 + r) * UU + kk * 16 + j * 4]);
    const int ow = o0 + (tid & 3);                 // matches reduce contract
    const float bias = bfc[ow];
    const bool writer = (tid & 12) == 0;
    const int ntiles = (BB * TT) / 32;             // 8192
    for (int tile = blockIdx.x; tile < ntiles; tile += gridDim.x) {
        const size_t rowbase = (size_t)tile * 32;
        const float4* hg = reinterpret_cast<const float4*>(hraw + rowbase * UU);
        #pragma unroll
        for (int i = 0; i < 4; ++i) {
            int v = tid + i * 512;                 // 0..2047 float4s
            int row = v >> 6, q = v & 63;
            float4 val = hg[v];
            *reinterpret_cast<float4*>(&hs[row * 320 + (q >> 2) * 20 + (q & 3) * 4]) = val;
        }
        __syncthreads();
        // raw values staged: zero killed units in the global hs output
        if (tid < 64) {
            int r = tid >> 1, c = (tid & 1) ? 7 : 3;
            hraw[(rowbase + r) * UU + c] = 0.f;
        }
        for (int r = 0; r < 32; ++r) {
            const float4* hrow = reinterpret_cast<const float4*>(&hs[r * 320 + kk * 20]);
            float4 a0 = {0,0,0,0}, a1 = {0,0,0,0}, a2 = {0,0,0,0}, a3 = {0,0,0,0};
            #pragma unroll
            for (int j = 0; j < 4; ++j) {
                float4 hv = hrow[j];
                fma4(a0, w[0][j], hv); fma4(a1, w[1][j], hv);
                fma4(a2, w[2][j], hv); fma4(a3, w[3][j], hv);
            }
            float s0 = (a0.x + a0.y) + (a0.z + a0.w);
            float s1 = (a1.x + a1.y) + (a1.z + a1.w);
            float s2 = (a2.x + a2.y) + (a2.z + a2.w);
            float s3 = (a3.x + a3.y) + (a3.z + a3.w);
            const bool e1 = (tid & 1), e2 = (tid & 2);
            float z0 = e1 ? s0 : s1;
            float z1 = e1 ? s2 : s3;
            float A0 = (e1 ? s1 : s0) + dpp_xor1(z0);
            float A1 = (e1 ? s3 : s2) + dpp_xor1(z1);
            float z2 = e2 ? A0 : A1;
            float C = (e2 ? A1 : A0) + dpp_xor2(z2);
            float C2 = C + dpp_xor8(C);            // + bit3 half
            float D  = C2 + swz_xor4(C2);          // + bit2 half (all 16 kk)
            if (writer) outR[(rowbase + r) * OO + ow] = D + bias;
        }
        __syncthreads();
    }
}

extern "C" void kernel_launch(void* const* d_in, const int* in_sizes, int n_in,
                              void* d_out, int out_size, void* d_ws, size_t ws_size,
                              hipStream_t stream) {
    const float* x   = (const float*)d_in[0];
    const float* Wih = (const float*)d_in[1];
    const float* Whh = (const float*)d_in[2];
    const float* bih = (const float*)d_in[3];
    const float* bhh = (const float*)d_in[4];
    const float* Wfc = (const float*)d_in[5];
    const float* bfc = (const float*)d_in[6];
    float* outR = (float*)d_out;                       // readouts [B,T,O]
    float* outH = outR + (size_t)BB * TT * OO;         // hs       [B,T,U]

    k_inproj<<<512, 512, 0, stream>>>(x, Wih, bih, bhh, outH);
    k_rnn<<<128, 512, 0, stream>>>(Whh, outH);
    k_readout<<<512, 512, 0, stream>>>(Wfc, bfc, outH, outR);
}

// Round 8
// 1597.602 us; speedup vs baseline: 1.1430x; 1.0143x over previous
//
#include <hip/hip_runtime.h>
#include <math.h>

#define BB 128
#define TT 2048
#define II 128
#define UU 256
#define OO 128

typedef __attribute__((ext_vector_type(8))) short bf16x8;
typedef __attribute__((ext_vector_type(4))) float f32x4;

// LDS-only barrier: orders LDS ops without draining vmcnt (global stores /
// prefetch loads stay in flight). sched_barrier(0) pins ordering (rule 18).
__device__ __forceinline__ void bar_lds() {
    __builtin_amdgcn_sched_barrier(0);
    asm volatile("s_waitcnt lgkmcnt(0)" ::: "memory");
    __builtin_amdgcn_s_barrier();
    __builtin_amdgcn_sched_barrier(0);
}

__device__ __forceinline__ void fma4(float4& a, const float4 w, const float4 h) {
    a.x = fmaf(w.x, h.x, a.x);
    a.y = fmaf(w.y, h.y, a.y);
    a.z = fmaf(w.z, h.z, a.z);
    a.w = fmaf(w.w, h.w, a.w);
}

// DPP cross-lane exchanges (pure VALU, no LDS pipe):
__device__ __forceinline__ float dpp_xor1(float x) {   // quad_perm [1,0,3,2]
    return __int_as_float(__builtin_amdgcn_mov_dpp(__float_as_int(x), 0xB1, 0xF, 0xF, true));
}
__device__ __forceinline__ float dpp_xor2(float x) {   // quad_perm [2,3,0,1]
    return __int_as_float(__builtin_amdgcn_mov_dpp(__float_as_int(x), 0x4E, 0xF, 0xF, true));
}
__device__ __forceinline__ float dpp_xor8(float x) {   // row_ror:8 (xor8 in 16)
    return __int_as_float(__builtin_amdgcn_mov_dpp(__float_as_int(x), 0x128, 0xF, 0xF, true));
}
__device__ __forceinline__ float swz_xor4(float x) {   // ds_swizzle xor4
    return __int_as_float(__builtin_amdgcn_ds_swizzle(__float_as_int(x), 0x101F));
}

// float -> bf16 round-to-nearest-even
__device__ __forceinline__ short f2bf(float f) {
    unsigned u = __float_as_uint(f);
    unsigned r = (u + 0x7FFFu + ((u >> 16) & 1u)) >> 16;
    return (short)r;
}

// 4-row value-splitting butterfly. CONTRACT: lane ends with the sum of row
// (tid & 3) of this group over the chunks of lane-bits {0,1,3}.
__device__ __forceinline__ float reduce4(float s0, float s1, float s2, float s3,
                                         int tid) {
    const bool e1 = (tid & 1), e2 = (tid & 2);
    float z0 = e1 ? s0 : s1;
    float z1 = e1 ? s2 : s3;
    float A0 = (e1 ? s1 : s0) + dpp_xor1(z0);   // row bit0
    float A1 = (e1 ? s3 : s2) + dpp_xor1(z1);   // row 2+bit0
    float z2 = e2 ? A0 : A1;
    float C = (e2 ? A1 : A0) + dpp_xor2(z2);    // row (tid&3)
    return C + dpp_xor8(C);                      // + lane-bit-3 chunks
}

// ---------------- Kernel 1: input projection ----------------
// (unchanged, validated since round 4)
__global__ __launch_bounds__(512, 2) void k_inproj(
    const float* __restrict__ x, const float* __restrict__ Wih,
    const float* __restrict__ bih, const float* __restrict__ bhh,
    float* __restrict__ xp)
{
    __shared__ __align__(16) float xs[64 * 160];   // 64 rows x 8 chunks x 20
    const int tid = threadIdx.x;
    const int kk = (tid & 3) | ((tid >> 1) & 4);   // bits 0,1,3
    const int G  = ((tid >> 2) & 1) | ((tid >> 4) << 1);   // 0..63
    const int u0 = G * 4;
    float4 w[4][4];
    #pragma unroll
    for (int r = 0; r < 4; ++r)
        #pragma unroll
        for (int j = 0; j < 4; ++j)
            w[r][j] = *reinterpret_cast<const float4*>(
                &Wih[(size_t)(u0 + r) * II + kk * 16 + j * 4]);
    const int r3 = tid & 3;                        // matches reduce4 contract
    const int uw = u0 + r3;
    const float bias = bih[uw] + bhh[uw];
    const bool writer = (tid & 8) == 0;
    const int ntiles = (BB * TT) / 64;             // 4096
    for (int tile = blockIdx.x; tile < ntiles; tile += gridDim.x) {
        const size_t rowbase = (size_t)tile * 64;
        const float4* xg = reinterpret_cast<const float4*>(x + rowbase * II);
        #pragma unroll
        for (int i = 0; i < 4; ++i) {
            int v = tid + i * 512;                 // 0..2047 float4s
            int row = v >> 5, q = v & 31;
            float4 val = xg[v];
            *reinterpret_cast<float4*>(&xs[row * 160 + (q >> 2) * 20 + (q & 3) * 4]) = val;
        }
        __syncthreads();
        for (int r = 0; r < 64; ++r) {
            const float4* hrow = reinterpret_cast<const float4*>(&xs[r * 160 + kk * 20]);
            float4 a0 = {0,0,0,0}, a1 = {0,0,0,0}, a2 = {0,0,0,0}, a3 = {0,0,0,0};
            #pragma unroll
            for (int j = 0; j < 4; ++j) {
                float4 hv = hrow[j];
                fma4(a0, w[0][j], hv); fma4(a1, w[1][j], hv);
                fma4(a2, w[2][j], hv); fma4(a3, w[3][j], hv);
            }
            float s0 = (a0.x + a0.y) + (a0.z + a0.w);
            float s1 = (a1.x + a1.y) + (a1.z + a1.w);
            float s2 = (a2.x + a2.y) + (a2.z + a2.w);
            float s3 = (a3.x + a3.y) + (a3.z + a3.w);
            float D = reduce4(s0, s1, s2, s3, tid);
            if (writer) xp[(rowbase + r) * UU + uw] = D + bias;
        }
        __syncthreads();
    }
}

// ---------------- Kernel 2: serial recurrence (MFMA, flat dep tree) ------
// 1 block/batch, 512 thr = 8 waves (2/SIMD). Per step: h (bf16, replicated
// across the 16 M-rows of A) x W_hh bf16 B fragments (2 n-tiles x 8 k-tiles
// in 64 VGPRs/lane). 16 MFMAs now target 8 INDEPENDENT accumulator slots
// (chain depth 2, was 8) + a 2-level VALU add tree on element 0. All acc
// indexing is compile-time (no scratch). Lane owns u = w*32+(g&1)*16+(lane
// &15) via C/D col=lane&15 (m89-verified). g<2 -> global h_raw writer;
// g>=2 -> masked bf16 LDS carry writer. ONE barrier per step.
__global__ __launch_bounds__(512, 2) void k_rnn(
    const float* __restrict__ Whh, float* __restrict__ xph)
{
    __shared__ __align__(16) short hbuf[2 * 256];  // 2 x 256 bf16 = 1 KB
    const int tid = threadIdx.x;
    const int w = tid >> 6;          // wave 0..7 -> u-range w*32..w*32+31
    const int lane = tid & 63;
    const int g = lane >> 4;         // k-group (A/B fragment row-group)
    const int c = lane & 15;         // tile column
    // B fragments: lane holds W_hh[u][kt*32 + g*8 .. +7] as 8 bf16.
    bf16x8 bq[2][8];
    #pragma unroll
    for (int q = 0; q < 2; ++q) {
        const int ub = w * 32 + q * 16 + c;
        #pragma unroll
        for (int kt = 0; kt < 8; ++kt) {
            const float* wp = &Whh[(size_t)ub * UU + kt * 32 + g * 8];
            float4 va = *reinterpret_cast<const float4*>(wp);
            float4 vb = *reinterpret_cast<const float4*>(wp + 4);
            bf16x8 v;
            v[0] = f2bf(va.x); v[1] = f2bf(va.y);
            v[2] = f2bf(va.z); v[3] = f2bf(va.w);
            v[4] = f2bf(vb.x); v[5] = f2bf(vb.y);
            v[6] = f2bf(vb.z); v[7] = f2bf(vb.w);
            bq[q][kt] = v;
        }
    }
    const int q = g & 1;                           // which n-tile this lane owns
    const int uxp = w * 32 + q * 16 + c;           // u this lane finalizes
    const bool gl = (g < 2);                       // global writer vs LDS writer
    const bool kill = (uxp == 3) || (uxp == 7);

    if (tid < 256) reinterpret_cast<int*>(hbuf)[tid] = 0;   // h0 = 0, both bufs
    __syncthreads();

    float* rowp = xph + (size_t)blockIdx.x * (size_t)TT * UU;
    float xpv = rowp[uxp];
    float xpn = rowp[UU + uxp];

    auto step = [&](int t, int p) {
        int tn = t + 2; tn = (tn < TT) ? tn : (TT - 1);     // branchless clamp
        float xpn2 = rowp[(size_t)tn * UU + uxp];
        const bf16x8* hb = reinterpret_cast<const bf16x8*>(hbuf + p * 256);
        // 8 independent accumulator slots: dep chain depth 2 (was 8)
        f32x4 acc0[4], acc1[4];
        #pragma unroll
        for (int i = 0; i < 4; ++i) {
            acc0[i] = (f32x4){0.f, 0.f, 0.f, 0.f};
            acc1[i] = (f32x4){0.f, 0.f, 0.f, 0.f};
        }
        #pragma unroll
        for (int kt = 0; kt < 8; ++kt) {
            bf16x8 a = hb[kt * 4 + g];             // 16-way broadcast read
            acc0[kt & 3] = __builtin_amdgcn_mfma_f32_16x16x32_bf16(a, bq[0][kt], acc0[kt & 3], 0, 0, 0);
            acc1[kt & 3] = __builtin_amdgcn_mfma_f32_16x16x32_bf16(a, bq[1][kt], acc1[kt & 3], 0, 0, 0);
        }
        // 2-level add tree on element 0 only (all indices compile-time)
        float d0 = (acc0[0][0] + acc0[1][0]) + (acc0[2][0] + acc0[3][0]);
        float d1 = (acc1[0][0] + acc1[1][0]) + (acc1[2][0] + acc1[3][0]);
        float Dres = q ? d1 : d0;
        float s = Dres + xpv;
        float hr = 1.0f - 2.0f / (__expf(2.0f * s) + 1.0f);
        if (gl) {
            rowp[(size_t)t * UU + uxp] = hr;                   // h_raw (fp32)
        } else {
            hbuf[(p ^ 1) * 256 + uxp] = kill ? (short)0 : f2bf(hr); // carry
        }
        bar_lds();
        xpv = xpn; xpn = xpn2;
    };
    for (int t = 0; t < TT; t += 2) { step(t, 0); step(t + 1, 1); }
}

// ---------------- Kernel 3: readout + mask fix-up ----------------
// (unchanged, validated since round 4)
__global__ __launch_bounds__(512, 2) void k_readout(
    const float* __restrict__ Wfc, const float* __restrict__ bfc,
    float* __restrict__ hraw, float* __restrict__ outR)
{
    __shared__ __align__(16) float hs[32 * 320];   // 32 rows x 16 chunks x 20
    const int tid = threadIdx.x;
    const int kk = tid & 15;
    const int G  = tid >> 4;                       // 0..31
    const int o0 = G * 4;
    float4 w[4][4];
    #pragma unroll
    for (int r = 0; r < 4; ++r)
        #pragma unroll
        for (int j = 0; j < 4; ++j)
            w[r][j] = *reinterpret_cast<const float4*>(
                &Wfc[(size_t)(o0 + r) * UU + kk * 16 + j * 4]);
    const int ow = o0 + (tid & 3);                 // matches reduce contract
    const float bias = bfc[ow];
    const bool writer = (tid & 12) == 0;
    const int ntiles = (BB * TT) / 32;             // 8192
    for (int tile = blockIdx.x; tile < ntiles; tile += gridDim.x) {
        const size_t rowbase = (size_t)tile * 32;
        const float4* hg = reinterpret_cast<const float4*>(hraw + rowbase * UU);
        #pragma unroll
        for (int i = 0; i < 4; ++i) {
            int v = tid + i * 512;                 // 0..2047 float4s
            int row = v >> 6, q = v & 63;
            float4 val = hg[v];
            *reinterpret_cast<float4*>(&hs[row * 320 + (q >> 2) * 20 + (q & 3) * 4]) = val;
        }
        __syncthreads();
        // raw values staged: zero killed units in the global hs output
        if (tid < 64) {
            int r = tid >> 1, c = (tid & 1) ? 7 : 3;
            hraw[(rowbase + r) * UU + c] = 0.f;
        }
        for (int r = 0; r < 32; ++r) {
            const float4* hrow = reinterpret_cast<const float4*>(&hs[r * 320 + kk * 20]);
            float4 a0 = {0,0,0,0}, a1 = {0,0,0,0}, a2 = {0,0,0,0}, a3 = {0,0,0,0};
            #pragma unroll
            for (int j = 0; j < 4; ++j) {
                float4 hv = hrow[j];
                fma4(a0, w[0][j], hv); fma4(a1, w[1][j], hv);
                fma4(a2, w[2][j], hv); fma4(a3, w[3][j], hv);
            }
            float s0 = (a0.x + a0.y) + (a0.z + a0.w);
            float s1 = (a1.x + a1.y) + (a1.z + a1.w);
            float s2 = (a2.x + a2.y) + (a2.z + a2.w);
            float s3 = (a3.x + a3.y) + (a3.z + a3.w);
            const bool e1 = (tid & 1), e2 = (tid & 2);
            float z0 = e1 ? s0 : s1;
            float z1 = e1 ? s2 : s3;
            float A0 = (e1 ? s1 : s0) + dpp_xor1(z0);
            float A1 = (e1 ? s3 : s2) + dpp_xor1(z1);
            float z2 = e2 ? A0 : A1;
            float C = (e2 ? A1 : A0) + dpp_xor2(z2);
            float C2 = C + dpp_xor8(C);            // + bit3 half
            float D  = C2 + swz_xor4(C2);          // + bit2 half (all 16 kk)
            if (writer) outR[(rowbase + r) * OO + ow] = D + bias;
        }
        __syncthreads();
    }
}

extern "C" void kernel_launch(void* const* d_in, const int* in_sizes, int n_in,
                              void* d_out, int out_size, void* d_ws, size_t ws_size,
                              hipStream_t stream) {
    const float* x   = (const float*)d_in[0];
    const float* Wih = (const float*)d_in[1];
    const float* Whh = (const float*)d_in[2];
    const float* bih = (const float*)d_in[3];
    const float* bhh = (const float*)d_in[4];
    const float* Wfc = (const float*)d_in[5];
    const float* bfc = (const float*)d_in[6];
    float* outR = (float*)d_out;                       // readouts [B,T,O]
    float* outH = outR + (size_t)BB * TT * OO;         // hs       [B,T,U]

    k_inproj<<<512, 512, 0, stream>>>(x, Wih, bih, bhh, outH);
    k_rnn<<<128, 512, 0, stream>>>(Whh, outH);
    k_readout<<<512, 512, 0, stream>>>(Wfc, bfc, outH, outR);
}

// Round 9
// 1448.358 us; speedup vs baseline: 1.2608x; 1.1030x over previous
//
#include <hip/hip_runtime.h>
#include <math.h>

#define BB 128
#define TT 2048
#define II 128
#define UU 256
#define OO 128

typedef __attribute__((ext_vector_type(8))) short bf16x8;
typedef __attribute__((ext_vector_type(4))) float f32x4;

#define MFMA16(a, b, cacc) __builtin_amdgcn_mfma_f32_16x16x32_bf16(a, b, cacc, 0, 0, 0)

// LDS-only barrier: orders LDS ops without draining vmcnt (global stores /
// prefetch loads stay in flight). sched_barrier(0) pins ordering (rule 18).
__device__ __forceinline__ void bar_lds() {
    __builtin_amdgcn_sched_barrier(0);
    asm volatile("s_waitcnt lgkmcnt(0)" ::: "memory");
    __builtin_amdgcn_s_barrier();
    __builtin_amdgcn_sched_barrier(0);
}

// float -> bf16 round-to-nearest-even
__device__ __forceinline__ short f2bf(float f) {
    unsigned u = __float_as_uint(f);
    unsigned r = (u + 0x7FFFu + ((u >> 16) & 1u)) >> 16;
    return (short)r;
}

__device__ __forceinline__ bf16x8 loadf8(const float* p) {
    float4 va = *reinterpret_cast<const float4*>(p);
    float4 vb = *reinterpret_cast<const float4*>(p + 4);
    bf16x8 v;
    v[0] = f2bf(va.x); v[1] = f2bf(va.y); v[2] = f2bf(va.z); v[3] = f2bf(va.w);
    v[4] = f2bf(vb.x); v[5] = f2bf(vb.y); v[6] = f2bf(vb.z); v[7] = f2bf(vb.w);
    return v;
}

// ---------------- Fully fused RNN: inproj + recurrence + readout ----------
// 1 block/batch, 512 thr = 8 waves (2/SIMD). All three GEMMs on the matrix
// pipe per step, sharing one barrier:
//   recurrence: h(t) = tanh(xp(t) + Whh . (mask*h(t-1)))   [16 MFMA]
//   xproj:      xp(t+2) = Wih . x(t+2) + bias              [ 8 MFMA, off-chain]
//   readout:    out(t-1) = Wfc . h_raw(t-1) + bfc          [ 8 MFMA, off-chain]
// hbuf carries MASKED h (validated r7/r8 path); raw h[3],h[7] ride a 2-float
// LDS sidecar and are added back to the readout exactly (no A-layout
// assumption needed). x is staged 4-deep in a bf16 LDS ring by wave 0.
// Lane owns u = w*32+(g&1)*16+c / o = w*16+c via C/D col=lane&15 (m89).
__global__ __launch_bounds__(512, 2) void k_fused(
    const float* __restrict__ x, const float* __restrict__ Wih,
    const float* __restrict__ Whh, const float* __restrict__ bih,
    const float* __restrict__ bhh, const float* __restrict__ Wfc,
    const float* __restrict__ bfc, float* __restrict__ outR,
    float* __restrict__ outH)
{
    __shared__ __align__(16) short hbuf[2 * 256];   // masked h, bf16, dbuf
    __shared__ __align__(16) short xbuf[4 * 128];   // x ring, bf16
    __shared__ __align__(16) float hside[2][2];     // raw h[3], h[7], dbuf

    const int tid = threadIdx.x;
    const int b = blockIdx.x;
    const int w = tid >> 6;          // wave 0..7
    const int lane = tid & 63;
    const int g = lane >> 4;         // fragment row-group
    const int c = lane & 15;         // tile column
    const int q = g & 1;             // n-tile this lane finalizes
    const int uxp = w * 32 + q * 16 + c;   // u for recurrence/hs
    const int ow  = w * 16 + c;            // o for readout
    const bool hswr  = (g < 2);            // writes hs (masked, fp32)
    const bool ldswr = (g >= 2);           // writes hbuf carry (masked, bf16)
    const bool kill = (uxp == 3) || (uxp == 7);

    // ---- weight fragments (bf16) ----
    bf16x8 bq[2][8];   // W_hh: lane (g,c) holds Whh[ub][kt*32+g*8..+7]
    bf16x8 wi[2][4];   // W_ih
    bf16x8 wf[8];      // W_fc (1 n-tile: o = w*16+c)
    #pragma unroll
    for (int q2 = 0; q2 < 2; ++q2) {
        const int ub = w * 32 + q2 * 16 + c;
        #pragma unroll
        for (int kt = 0; kt < 8; ++kt)
            bq[q2][kt] = loadf8(&Whh[(size_t)ub * UU + kt * 32 + g * 8]);
        #pragma unroll
        for (int kt = 0; kt < 4; ++kt)
            wi[q2][kt] = loadf8(&Wih[(size_t)ub * II + kt * 32 + g * 8]);
    }
    #pragma unroll
    for (int kt = 0; kt < 8; ++kt)
        wf[kt] = loadf8(&Wfc[(size_t)ow * UU + kt * 32 + g * 8]);
    const float biasu = bih[uxp] + bhh[uxp];
    const float bfc_s = bfc[ow];
    const float wfc3 = Wfc[(size_t)ow * UU + 3];
    const float wfc7 = Wfc[(size_t)ow * UU + 7];

    // ---- init LDS state ----
    if (tid < 256) reinterpret_cast<int*>(hbuf)[tid] = 0;       // h(-1) = 0
    if (tid >= 256 && tid < 260)
        reinterpret_cast<float*>(hside)[tid - 256] = 0.f;

    // ---- stage x[0..2] into ring slots 0..2; x[3] into regs ----
    const float* xb = x + (size_t)b * (size_t)TT * II;
    const int xl = tid & 31;
    if (tid < 96) {
        int slot = tid >> 5;
        float4 v = *reinterpret_cast<const float4*>(xb + slot * II + xl * 4);
        short4 s4 = { f2bf(v.x), f2bf(v.y), f2bf(v.z), f2bf(v.w) };
        *reinterpret_cast<short4*>(&xbuf[slot * 128 + xl * 4]) = s4;
    }
    float4 xr = {0.f, 0.f, 0.f, 0.f};
    if (tid < 32)
        xr = *reinterpret_cast<const float4*>(xb + 3 * II + xl * 4);
    __syncthreads();

    // xp via MFMA from ring slot (off the h critical chain)
    auto xproj = [&](int slot) -> float {
        f32x4 xa0 = {0.f,0.f,0.f,0.f}, xa1 = {0.f,0.f,0.f,0.f};
        #pragma unroll
        for (int kt = 0; kt < 4; ++kt) {
            bf16x8 ax = *reinterpret_cast<const bf16x8*>(
                &xbuf[slot * 128 + kt * 32 + g * 8]);
            xa0 = MFMA16(ax, wi[0][kt], xa0);
            xa1 = MFMA16(ax, wi[1][kt], xa1);
        }
        return (q ? xa1[0] : xa0[0]) + biasu;
    };

    float xpv = xproj(0);
    float xpn = xproj(1);

    float* hsrow = outH + (size_t)b * (size_t)TT * UU;
    float* rorow = outR + (size_t)b * (size_t)TT * OO;

    auto step = [&](int t, int p) {
        // x ring: write slot t+3 from regs, issue load of x[t+4]
        if (tid < 32) {
            int ws = (t + 3) & 3;
            short4 s4 = { f2bf(xr.x), f2bf(xr.y), f2bf(xr.z), f2bf(xr.w) };
            *reinterpret_cast<short4*>(&xbuf[ws * 128 + xl * 4]) = s4;
            int tl = t + 4; tl = (tl < TT) ? tl : (TT - 1);
            xr = *reinterpret_cast<const float4*>(xb + (size_t)tl * II + xl * 4);
        }
        // A-fragments: masked h(t-1) (shared by recurrence AND readout)
        bf16x8 af[8];
        #pragma unroll
        for (int kt = 0; kt < 8; ++kt)
            af[kt] = *reinterpret_cast<const bf16x8*>(
                &hbuf[p * 256 + kt * 32 + g * 8]);
        float hr3 = hside[p][0], hr7 = hside[p][1];
        // recurrence: 16 MFMA, 2 acc slots per n-tile
        f32x4 r00 = {0.f,0.f,0.f,0.f}, r01 = {0.f,0.f,0.f,0.f};
        f32x4 r10 = {0.f,0.f,0.f,0.f}, r11 = {0.f,0.f,0.f,0.f};
        #pragma unroll
        for (int kt = 0; kt < 8; kt += 2) {
            r00 = MFMA16(af[kt],     bq[0][kt],     r00);
            r10 = MFMA16(af[kt],     bq[1][kt],     r10);
            r01 = MFMA16(af[kt + 1], bq[0][kt + 1], r01);
            r11 = MFMA16(af[kt + 1], bq[1][kt + 1], r11);
        }
        // readout of h(t-1): 8 MFMA on the same fragments
        f32x4 o0 = {0.f,0.f,0.f,0.f}, o1 = {0.f,0.f,0.f,0.f};
        #pragma unroll
        for (int kt = 0; kt < 8; kt += 2) {
            o0 = MFMA16(af[kt],     wf[kt],     o0);
            o1 = MFMA16(af[kt + 1], wf[kt + 1], o1);
        }
        // xp(t+2), off-chain
        float xpn2 = xproj((t + 2) & 3);
        // finish recurrence
        float Dres = q ? (r10[0] + r11[0]) : (r00[0] + r01[0]);
        float s = Dres + xpv;
        float hr = 1.0f - 2.0f / (__expf(2.0f * s) + 1.0f);
        // hs output (masked, fp32)
        if (hswr) hsrow[(size_t)t * UU + uxp] = kill ? 0.f : hr;
        // readout output (exact raw-h via sidecar correction)
        float ro = (o0[0] + o1[0]) + hr3 * wfc3 + hr7 * wfc7 + bfc_s;
        if (t > 0 && g == 0) rorow[(size_t)(t - 1) * OO + ow] = ro;
        // carry: masked bf16 h + raw sidecar
        if (ldswr) {
            hbuf[(p ^ 1) * 256 + uxp] = kill ? (short)0 : f2bf(hr);
            if (w == 0 && g == 2) {
                if (c == 3) hside[p ^ 1][0] = hr;
                if (c == 7) hside[p ^ 1][1] = hr;
            }
        }
        bar_lds();
        xpv = xpn; xpn = xpn2;
    };
    for (int t = 0; t < TT; t += 2) { step(t, 0); step(t + 1, 1); }

    // epilogue: readout of h(TT-1) (lives in hbuf[TT&1 == 0])
    {
        bf16x8 af[8];
        #pragma unroll
        for (int kt = 0; kt < 8; ++kt)
            af[kt] = *reinterpret_cast<const bf16x8*>(&hbuf[kt * 32 + g * 8]);
        float hr3 = hside[0][0], hr7 = hside[0][1];
        f32x4 o0 = {0.f,0.f,0.f,0.f}, o1 = {0.f,0.f,0.f,0.f};
        #pragma unroll
        for (int kt = 0; kt < 8; kt += 2) {
            o0 = MFMA16(af[kt],     wf[kt],     o0);
            o1 = MFMA16(af[kt + 1], wf[kt + 1], o1);
        }
        float ro = (o0[0] + o1[0]) + hr3 * wfc3 + hr7 * wfc7 + bfc_s;
        if (g == 0) rorow[(size_t)(TT - 1) * OO + ow] = ro;
    }
}

extern "C" void kernel_launch(void* const* d_in, const int* in_sizes, int n_in,
                              void* d_out, int out_size, void* d_ws, size_t ws_size,
                              hipStream_t stream) {
    const float* x   = (const float*)d_in[0];
    const float* Wih = (const float*)d_in[1];
    const float* Whh = (const float*)d_in[2];
    const float* bih = (const float*)d_in[3];
    const float* bhh = (const float*)d_in[4];
    const float* Wfc = (const float*)d_in[5];
    const float* bfc = (const float*)d_in[6];
    float* outR = (float*)d_out;                       // readouts [B,T,O]
    float* outH = outR + (size_t)BB * TT * OO;         // hs       [B,T,U]

    k_fused<<<128, 512, 0, stream>>>(x, Wih, Whh, bih, bhh, Wfc, bfc, outR, outH);
}

// Round 10
// 1426.188 us; speedup vs baseline: 1.2804x; 1.0155x over previous
//
#include <hip/hip_runtime.h>
#include <math.h>

#define BB 128
#define TT 2048
#define II 128
#define UU 256
#define OO 128

typedef __attribute__((ext_vector_type(8))) short bf16x8;
typedef __attribute__((ext_vector_type(4))) float f32x4;

#define MFMA16(a, b, cacc) __builtin_amdgcn_mfma_f32_16x16x32_bf16(a, b, cacc, 0, 0, 0)

// LDS-only barrier: orders LDS ops without draining vmcnt (global stores /
// prefetch loads stay in flight). sched_barrier(0) pins ordering (rule 18).
__device__ __forceinline__ void bar_lds() {
    __builtin_amdgcn_sched_barrier(0);
    asm volatile("s_waitcnt lgkmcnt(0)" ::: "memory");
    __builtin_amdgcn_s_barrier();
    __builtin_amdgcn_sched_barrier(0);
}

// float -> bf16 round-to-nearest-even
__device__ __forceinline__ short f2bf(float f) {
    unsigned u = __float_as_uint(f);
    unsigned r = (u + 0x7FFFu + ((u >> 16) & 1u)) >> 16;
    return (short)r;
}

__device__ __forceinline__ bf16x8 loadf8(const float* p) {
    float4 va = *reinterpret_cast<const float4*>(p);
    float4 vb = *reinterpret_cast<const float4*>(p + 4);
    bf16x8 v;
    v[0] = f2bf(va.x); v[1] = f2bf(va.y); v[2] = f2bf(va.z); v[3] = f2bf(va.w);
    v[4] = f2bf(vb.x); v[5] = f2bf(vb.y); v[6] = f2bf(vb.z); v[7] = f2bf(vb.w);
    return v;
}

// ---------------- Fully fused RNN, role-split waves -----------------------
// 1 block/batch, 1024 thr = 16 waves (4/SIMD).
//   waves 0-7  (recurrence): h(t)=tanh(xp(t)+Whh.(mask*h(t-1))) — 16 MFMA,
//              tanh, carry write. Shortest possible inter-barrier body.
//   waves 8-15 (helpers): readout(t-1) from stable hbuf[p] (8 MFMA),
//              xproj(t+2) -> xpring (8 MFMA), x staging. All off the
//              h critical chain; handoffs are >= 2 barriers apart.
// ONE bar_lds per step, executed by both role loops (wave-uniform branch,
// equal barrier counts). Weight sets (bq | wi+wf) live in disjoint branches
// so the allocator overlays their registers (~64 VGPR each).
// hbuf carries MASKED bf16 h (r7/r8-validated); raw h[3],h[7] ride the
// hside sidecar and are added back to readout exactly.
__global__ __launch_bounds__(1024, 4) void k_fused(
    const float* __restrict__ x, const float* __restrict__ Wih,
    const float* __restrict__ Whh, const float* __restrict__ bih,
    const float* __restrict__ bhh, const float* __restrict__ Wfc,
    const float* __restrict__ bfc, float* __restrict__ outR,
    float* __restrict__ outH)
{
    __shared__ __align__(16) short hbuf[2 * 256];   // masked h, bf16, dbuf
    __shared__ __align__(16) short xbuf[4 * 128];   // x ring, bf16
    __shared__ __align__(16) float xpring[4 * 256]; // xp handoff ring
    __shared__ __align__(16) float hside[2][2];     // raw h[3], h[7], dbuf

    const int tid = threadIdx.x;
    const int b = blockIdx.x;
    const int w = tid >> 6;          // wave 0..15
    const int lane = tid & 63;
    const int g = lane >> 4;         // fragment row-group
    const int c = lane & 15;         // tile column
    const int q = g & 1;             // n-tile this lane finalizes

    const float* xb = x + (size_t)b * (size_t)TT * II;
    float* hsrow = outH + (size_t)b * (size_t)TT * UU;
    float* rorow = outR + (size_t)b * (size_t)TT * OO;

    if (w < 8) {
        // ================= recurrence waves =================
        const int uxp = w * 32 + q * 16 + c;
        const bool kill = (uxp == 3) || (uxp == 7);
        bf16x8 bq[2][8];
        #pragma unroll
        for (int q2 = 0; q2 < 2; ++q2) {
            const int ub = w * 32 + q2 * 16 + c;
            #pragma unroll
            for (int kt = 0; kt < 8; ++kt)
                bq[q2][kt] = loadf8(&Whh[(size_t)ub * UU + kt * 32 + g * 8]);
        }
        if (tid < 256) reinterpret_cast<int*>(hbuf)[tid] = 0;   // h(-1)=0
        if (tid < 4) reinterpret_cast<float*>(hside)[tid] = 0.f;
        bar_lds();                       // sync1: x staged by helpers
        bar_lds();                       // sync2: xp(0),xp(1) in ring
        for (int t = 0; t < TT; ++t) {
            const int p = t & 1;
            float xpv = xpring[(t & 3) * 256 + uxp];
            bf16x8 af[8];
            #pragma unroll
            for (int kt = 0; kt < 8; ++kt)
                af[kt] = *reinterpret_cast<const bf16x8*>(
                    &hbuf[p * 256 + kt * 32 + g * 8]);
            f32x4 r00 = {0.f,0.f,0.f,0.f}, r01 = {0.f,0.f,0.f,0.f};
            f32x4 r10 = {0.f,0.f,0.f,0.f}, r11 = {0.f,0.f,0.f,0.f};
            #pragma unroll
            for (int kt = 0; kt < 8; kt += 2) {
                r00 = MFMA16(af[kt],     bq[0][kt],     r00);
                r10 = MFMA16(af[kt],     bq[1][kt],     r10);
                r01 = MFMA16(af[kt + 1], bq[0][kt + 1], r01);
                r11 = MFMA16(af[kt + 1], bq[1][kt + 1], r11);
            }
            float Dres = q ? (r10[0] + r11[0]) : (r00[0] + r01[0]);
            float s = Dres + xpv;
            float hr = 1.0f - 2.0f / (__expf(2.0f * s) + 1.0f);
            if (g < 2) {
                hsrow[(size_t)t * UU + uxp] = kill ? 0.f : hr;   // hs out
            } else {
                hbuf[(p ^ 1) * 256 + uxp] = kill ? (short)0 : f2bf(hr);
                if (w == 0 && g == 2) {
                    if (c == 3) hside[p ^ 1][0] = hr;
                    if (c == 7) hside[p ^ 1][1] = hr;
                }
            }
            bar_lds();
        }
    } else {
        // ================= helper waves =================
        const int hw = w - 8;
        const int ow  = hw * 16 + c;            // readout o
        const int uxh = hw * 32 + q * 16 + c;   // xproj u
        bf16x8 wi[2][4], wf[8];
        #pragma unroll
        for (int q2 = 0; q2 < 2; ++q2) {
            const int ub = hw * 32 + q2 * 16 + c;
            #pragma unroll
            for (int kt = 0; kt < 4; ++kt)
                wi[q2][kt] = loadf8(&Wih[(size_t)ub * II + kt * 32 + g * 8]);
        }
        #pragma unroll
        for (int kt = 0; kt < 8; ++kt)
            wf[kt] = loadf8(&Wfc[(size_t)ow * UU + kt * 32 + g * 8]);
        const float biasu = bih[uxh] + bhh[uxh];
        const float bfc_s = bfc[ow];
        const float wfc3 = Wfc[(size_t)ow * UU + 3];
        const float wfc7 = Wfc[(size_t)ow * UU + 7];
        // stage x[0..3] into ring; x[4] into regs
        const int xl = lane & 31;
        float4 xr = {0.f, 0.f, 0.f, 0.f};
        if (hw < 2) {
            int slot = hw * 2 + (lane >> 5);
            float4 v = *reinterpret_cast<const float4*>(xb + slot * II + xl * 4);
            short4 s4 = { f2bf(v.x), f2bf(v.y), f2bf(v.z), f2bf(v.w) };
            *reinterpret_cast<short4*>(&xbuf[slot * 128 + xl * 4]) = s4;
        }
        if (hw == 0 && lane < 32)
            xr = *reinterpret_cast<const float4*>(xb + 4 * II + xl * 4);
        bar_lds();                       // sync1: x staged
        #pragma unroll
        for (int s0 = 0; s0 < 2; ++s0) { // xp(0), xp(1)
            f32x4 xa0 = {0.f,0.f,0.f,0.f}, xa1 = {0.f,0.f,0.f,0.f};
            #pragma unroll
            for (int kt = 0; kt < 4; ++kt) {
                bf16x8 ax = *reinterpret_cast<const bf16x8*>(
                    &xbuf[s0 * 128 + kt * 32 + g * 8]);
                xa0 = MFMA16(ax, wi[0][kt], xa0);
                xa1 = MFMA16(ax, wi[1][kt], xa1);
            }
            if (g < 2) xpring[s0 * 256 + uxh] = (q ? xa1[0] : xa0[0]) + biasu;
        }
        bar_lds();                       // sync2
        for (int t = 0; t < TT; ++t) {
            const int p = t & 1;
            // x ring: write x(t+4) from regs, load x(t+5)
            if (hw == 0 && lane < 32) {
                short4 s4 = { f2bf(xr.x), f2bf(xr.y), f2bf(xr.z), f2bf(xr.w) };
                *reinterpret_cast<short4*>(&xbuf[((t + 4) & 3) * 128 + xl * 4]) = s4;
                int tl = t + 5; tl = (tl < TT) ? tl : (TT - 1);
                xr = *reinterpret_cast<const float4*>(xb + (size_t)tl * II + xl * 4);
            }
            // readout(t-1) from stable hbuf[p]
            bf16x8 af[8];
            #pragma unroll
            for (int kt = 0; kt < 8; ++kt)
                af[kt] = *reinterpret_cast<const bf16x8*>(
                    &hbuf[p * 256 + kt * 32 + g * 8]);
            f32x4 o0 = {0.f,0.f,0.f,0.f}, o1 = {0.f,0.f,0.f,0.f};
            #pragma unroll
            for (int kt = 0; kt < 8; kt += 2) {
                o0 = MFMA16(af[kt],     wf[kt],     o0);
                o1 = MFMA16(af[kt + 1], wf[kt + 1], o1);
            }
            float hr3 = hside[p][0], hr7 = hside[p][1];
            float ro = (o0[0] + o1[0]) + hr3 * wfc3 + hr7 * wfc7 + bfc_s;
            if (t > 0 && g == 0) rorow[(size_t)(t - 1) * OO + ow] = ro;
            // xproj(t+2) -> ring (read at t+2, two barriers later)
            f32x4 xa0 = {0.f,0.f,0.f,0.f}, xa1 = {0.f,0.f,0.f,0.f};
            #pragma unroll
            for (int kt = 0; kt < 4; ++kt) {
                bf16x8 ax = *reinterpret_cast<const bf16x8*>(
                    &xbuf[((t + 2) & 3) * 128 + kt * 32 + g * 8]);
                xa0 = MFMA16(ax, wi[0][kt], xa0);
                xa1 = MFMA16(ax, wi[1][kt], xa1);
            }
            if (g < 2) xpring[((t + 2) & 3) * 256 + uxh] = (q ? xa1[0] : xa0[0]) + biasu;
            bar_lds();
        }
        // epilogue: readout(TT-1); h(TT-1) is in hbuf[0], raws in hside[0]
        {
            bf16x8 af[8];
            #pragma unroll
            for (int kt = 0; kt < 8; ++kt)
                af[kt] = *reinterpret_cast<const bf16x8*>(&hbuf[kt * 32 + g * 8]);
            f32x4 o0 = {0.f,0.f,0.f,0.f}, o1 = {0.f,0.f,0.f,0.f};
            #pragma unroll
            for (int kt = 0; kt < 8; kt += 2) {
                o0 = MFMA16(af[kt],     wf[kt],     o0);
                o1 = MFMA16(af[kt + 1], wf[kt + 1], o1);
            }
            float ro = (o0[0] + o1[0]) + hside[0][0] * wfc3 + hside[0][1] * wfc7 + bfc_s;
            if (g == 0) rorow[(size_t)(TT - 1) * OO + ow] = ro;
        }
    }
}

extern "C" void kernel_launch(void* const* d_in, const int* in_sizes, int n_in,
                              void* d_out, int out_size, void* d_ws, size_t ws_size,
                              hipStream_t stream) {
    const float* x   = (const float*)d_in[0];
    const float* Wih = (const float*)d_in[1];
    const float* Whh = (const float*)d_in[2];
    const float* bih = (const float*)d_in[3];
    const float* bhh = (const float*)d_in[4];
    const float* Wfc = (const float*)d_in[5];
    const float* bfc = (const float*)d_in[6];
    float* outR = (float*)d_out;                       // readouts [B,T,O]
    float* outH = outR + (size_t)BB * TT * OO;         // hs       [B,T,U]

    k_fused<<<128, 1024, 0, stream>>>(x, Wih, Whh, bih, bhh, Wfc, bfc, outR, outH);
}

// Round 11
// 1254.150 us; speedup vs baseline: 1.4560x; 1.1372x over previous
//
#include <hip/hip_runtime.h>
#include <math.h>

#define BB 128
#define TT 2048
#define II 128
#define UU 256
#define OO 128

typedef __attribute__((ext_vector_type(8))) short bf16x8;
typedef __attribute__((ext_vector_type(4))) float f32x4;

#define MFMA16(a, b, cacc) __builtin_amdgcn_mfma_f32_16x16x32_bf16(a, b, cacc, 0, 0, 0)

// LDS-only barrier (rule 18): orders LDS ops without draining vmcnt.
__device__ __forceinline__ void bar_lds() {
    __builtin_amdgcn_sched_barrier(0);
    asm volatile("s_waitcnt lgkmcnt(0)" ::: "memory");
    __builtin_amdgcn_s_barrier();
    __builtin_amdgcn_sched_barrier(0);
}

// float -> bf16 round-to-nearest-even
__device__ __forceinline__ short f2bf(float f) {
    unsigned u = __float_as_uint(f);
    unsigned r = (u + 0x7FFFu + ((u >> 16) & 1u)) >> 16;
    return (short)r;
}

__device__ __forceinline__ bf16x8 loadf8(const float* p) {
    float4 va = *reinterpret_cast<const float4*>(p);
    float4 vb = *reinterpret_cast<const float4*>(p + 4);
    bf16x8 v;
    v[0] = f2bf(va.x); v[1] = f2bf(va.y); v[2] = f2bf(va.z); v[3] = f2bf(va.w);
    v[4] = f2bf(vb.x); v[5] = f2bf(vb.y); v[6] = f2bf(vb.z); v[7] = f2bf(vb.w);
    return v;
}

// ---------------- Kernel 1: input projection as MFMA GEMM -----------------
// xp[row,u] = x[row,:].Wih[u,:] + bih[u] + bhh[u].  M=262144, N=256, K=128.
// 256 thr = 4 waves; tile = 64 rows. Wave w owns n-range w*64 (4 n-tiles).
// x tile staged bf16 in LDS with T2 XOR swizzle (16B-chunk ^ (row&7)<<4) so
// A-fragment reads (16 lanes @ row stride 256B) are conflict-free.
__global__ __launch_bounds__(256, 2) void k_inproj(
    const float* __restrict__ x, const float* __restrict__ Wih,
    const float* __restrict__ bih, const float* __restrict__ bhh,
    float* __restrict__ xp)
{
    __shared__ __align__(16) short xs[64 * 128];   // 16 KB bf16, swizzled
    const int tid = threadIdx.x;
    const int w = tid >> 6;
    const int lane = tid & 63;
    const int g = lane >> 4;
    const int c = lane & 15;
    // B fragments (stationary): Wih[u][kt*32+g*8..+7], u = w*64+nt*16+c
    bf16x8 wb[4][4];
    float bias[4];
    #pragma unroll
    for (int nt = 0; nt < 4; ++nt) {
        const int u = w * 64 + nt * 16 + c;
        #pragma unroll
        for (int kt = 0; kt < 4; ++kt)
            wb[nt][kt] = loadf8(&Wih[(size_t)u * II + kt * 32 + g * 8]);
        bias[nt] = bih[u] + bhh[u];
    }
    const int srow = tid >> 2, sq = tid & 3;       // staging: 4 thr/row
    const int ntiles = (BB * TT) / 64;             // 4096
    for (int tile = blockIdx.x; tile < ntiles; tile += gridDim.x) {
        const size_t rowbase = (size_t)tile * 64;
        // stage 64x128 fp32 -> bf16 swizzled
        #pragma unroll
        for (int t2 = 0; t2 < 4; ++t2) {
            int n = sq * 4 + t2;                   // 16B chunk index 0..15
            const float* src = &x[(rowbase + srow) * II + n * 8];
            bf16x8 v = loadf8(src);
            int off = srow * 128 + ((n * 8) ^ ((srow & 7) << 3));
            *reinterpret_cast<bf16x8*>(&xs[off]) = v;
        }
        __syncthreads();
        #pragma unroll
        for (int mt = 0; mt < 4; ++mt) {
            const int row = mt * 16 + c;
            bf16x8 af[4];
            #pragma unroll
            for (int kt = 0; kt < 4; ++kt)
                af[kt] = *reinterpret_cast<const bf16x8*>(
                    &xs[row * 128 + ((kt * 32 + g * 8) ^ ((c & 7) << 3))]);
            f32x4 acc[4];
            #pragma unroll
            for (int nt = 0; nt < 4; ++nt) acc[nt] = (f32x4){0.f,0.f,0.f,0.f};
            #pragma unroll
            for (int kt = 0; kt < 4; ++kt)
                #pragma unroll
                for (int nt = 0; nt < 4; ++nt)
                    acc[nt] = MFMA16(af[kt], wb[nt][kt], acc[nt]);
            #pragma unroll
            for (int nt = 0; nt < 4; ++nt)
                #pragma unroll
                for (int r = 0; r < 4; ++r)
                    xp[(rowbase + mt * 16 + g * 4 + r) * UU + w * 64 + nt * 16 + c]
                        = acc[nt][r] + bias[nt];
        }
        __syncthreads();
    }
}

// ---------------- Kernel 2: serial recurrence (r8, measured 546 ns/step) --
// 1 block/batch, 512 thr = 8 waves (2/SIMD). h (bf16, replicated A) x
// W_hh bf16 B fragments; 16 MFMA into 8 independent acc slots (depth 2).
// Lane owns u = w*32+(g&1)*16+(lane&15) via C/D col=lane&15. g<2 lanes
// write h_raw (fp32) to global; g>=2 write masked bf16 LDS carry.
__global__ __launch_bounds__(512, 2) void k_rnn(
    const float* __restrict__ Whh, float* __restrict__ xph)
{
    __shared__ __align__(16) short hbuf[2 * 256];  // 2 x 256 bf16 = 1 KB
    const int tid = threadIdx.x;
    const int w = tid >> 6;
    const int lane = tid & 63;
    const int g = lane >> 4;
    const int c = lane & 15;
    bf16x8 bq[2][8];
    #pragma unroll
    for (int q2 = 0; q2 < 2; ++q2) {
        const int ub = w * 32 + q2 * 16 + c;
        #pragma unroll
        for (int kt = 0; kt < 8; ++kt)
            bq[q2][kt] = loadf8(&Whh[(size_t)ub * UU + kt * 32 + g * 8]);
    }
    const int q = g & 1;
    const int uxp = w * 32 + q * 16 + c;
    const bool gl = (g < 2);
    const bool kill = (uxp == 3) || (uxp == 7);

    if (tid < 256) reinterpret_cast<int*>(hbuf)[tid] = 0;
    __syncthreads();

    float* rowp = xph + (size_t)blockIdx.x * (size_t)TT * UU;
    float xpv = rowp[uxp];
    float xpn = rowp[UU + uxp];

    auto step = [&](int t, int p) {
        int tn = t + 2; tn = (tn < TT) ? tn : (TT - 1);
        float xpn2 = rowp[(size_t)tn * UU + uxp];
        const bf16x8* hb = reinterpret_cast<const bf16x8*>(hbuf + p * 256);
        f32x4 acc0[4], acc1[4];
        #pragma unroll
        for (int i = 0; i < 4; ++i) {
            acc0[i] = (f32x4){0.f, 0.f, 0.f, 0.f};
            acc1[i] = (f32x4){0.f, 0.f, 0.f, 0.f};
        }
        #pragma unroll
        for (int kt = 0; kt < 8; ++kt) {
            bf16x8 a = hb[kt * 4 + g];
            acc0[kt & 3] = MFMA16(a, bq[0][kt], acc0[kt & 3]);
            acc1[kt & 3] = MFMA16(a, bq[1][kt], acc1[kt & 3]);
        }
        float d0 = (acc0[0][0] + acc0[1][0]) + (acc0[2][0] + acc0[3][0]);
        float d1 = (acc1[0][0] + acc1[1][0]) + (acc1[2][0] + acc1[3][0]);
        float Dres = q ? d1 : d0;
        float s = Dres + xpv;
        float hr = 1.0f - 2.0f / (__expf(2.0f * s) + 1.0f);
        if (gl) {
            rowp[(size_t)t * UU + uxp] = hr;                    // h_raw (fp32)
        } else {
            hbuf[(p ^ 1) * 256 + uxp] = kill ? (short)0 : f2bf(hr);
        }
        bar_lds();
        xpv = xpn; xpn = xpn2;
    };
    for (int t = 0; t < TT; t += 2) { step(t, 0); step(t + 1, 1); }
}

// ---------------- Kernel 3: readout as MFMA GEMM + mask fix-up ------------
// readout[row,o] = h_raw[row,:].Wfc[o,:] + bfc[o].  M=262144, N=128, K=256.
// 256 thr = 4 waves; tile = 64 rows; wave w owns n-range w*32 (2 n-tiles).
// h_raw staged bf16 swizzled; after staging, cols {3,7} of global h_raw are
// zeroed so the hs output becomes the masked hidden state.
__global__ __launch_bounds__(256, 2) void k_readout(
    const float* __restrict__ Wfc, const float* __restrict__ bfc,
    float* __restrict__ hraw, float* __restrict__ outR)
{
    __shared__ __align__(16) short hs[64 * 256];   // 32 KB bf16, swizzled
    const int tid = threadIdx.x;
    const int w = tid >> 6;
    const int lane = tid & 63;
    const int g = lane >> 4;
    const int c = lane & 15;
    bf16x8 wb[2][8];
    float bias[2];
    #pragma unroll
    for (int nt = 0; nt < 2; ++nt) {
        const int o = w * 32 + nt * 16 + c;
        #pragma unroll
        for (int kt = 0; kt < 8; ++kt)
            wb[nt][kt] = loadf8(&Wfc[(size_t)o * UU + kt * 32 + g * 8]);
        bias[nt] = bfc[o];
    }
    const int srow = tid >> 2, sq = tid & 3;       // staging: 4 thr/row
    const int ntiles = (BB * TT) / 64;             // 4096
    for (int tile = blockIdx.x; tile < ntiles; tile += gridDim.x) {
        const size_t rowbase = (size_t)tile * 64;
        #pragma unroll
        for (int t2 = 0; t2 < 8; ++t2) {
            int n = sq * 8 + t2;                   // 16B chunk 0..31
            const float* src = &hraw[(rowbase + srow) * UU + n * 8];
            bf16x8 v = loadf8(src);
            int off = srow * 256 + ((n * 8) ^ ((srow & 7) << 3));
            *reinterpret_cast<bf16x8*>(&hs[off]) = v;
        }
        __syncthreads();
        // raw values staged: zero killed units in the global hs output
        if (tid < 128) {
            int r = tid >> 1, col = (tid & 1) ? 7 : 3;
            hraw[(rowbase + r) * UU + col] = 0.f;
        }
        #pragma unroll
        for (int mt = 0; mt < 4; ++mt) {
            const int row = mt * 16 + c;
            f32x4 acc[2];
            acc[0] = (f32x4){0.f,0.f,0.f,0.f};
            acc[1] = (f32x4){0.f,0.f,0.f,0.f};
            #pragma unroll
            for (int kt = 0; kt < 8; ++kt) {
                bf16x8 af = *reinterpret_cast<const bf16x8*>(
                    &hs[row * 256 + ((kt * 32 + g * 8) ^ ((c & 7) << 3))]);
                acc[0] = MFMA16(af, wb[0][kt], acc[0]);
                acc[1] = MFMA16(af, wb[1][kt], acc[1]);
            }
            #pragma unroll
            for (int nt = 0; nt < 2; ++nt)
                #pragma unroll
                for (int r = 0; r < 4; ++r)
                    outR[(rowbase + mt * 16 + g * 4 + r) * OO + w * 32 + nt * 16 + c]
                        = acc[nt][r] + bias[nt];
        }
        __syncthreads();
    }
}

extern "C" void kernel_launch(void* const* d_in, const int* in_sizes, int n_in,
                              void* d_out, int out_size, void* d_ws, size_t ws_size,
                              hipStream_t stream) {
    const float* x   = (const float*)d_in[0];
    const float* Wih = (const float*)d_in[1];
    const float* Whh = (const float*)d_in[2];
    const float* bih = (const float*)d_in[3];
    const float* bhh = (const float*)d_in[4];
    const float* Wfc = (const float*)d_in[5];
    const float* bfc = (const float*)d_in[6];
    float* outR = (float*)d_out;                       // readouts [B,T,O]
    float* outH = outR + (size_t)BB * TT * OO;         // hs       [B,T,U]

    k_inproj<<<512, 256, 0, stream>>>(x, Wih, bih, bhh, outH);
    k_rnn<<<128, 512, 0, stream>>>(Whh, outH);
    k_readout<<<512, 256, 0, stream>>>(Wfc, bfc, outH, outR);
}